// Round 1
// baseline (943.326 us; speedup 1.0000x reference)
//
#include <hip/hip_runtime.h>
#include <hip/hip_bf16.h>

namespace {
constexpr int kB   = 4;
constexpr int kL   = 2048;
constexpr int kLc  = 2051;   // L + 3
constexpr int kD   = 1024;
constexpr int kS   = 64;
constexpr int kM   = kB * kLc;  // 8204 flattened (b,t) rows
constexpr int kMT  = 32;        // proj rows per block
constexpr int kNC  = 196;       // 64 U + 64 B + 64 C + 4 d1
constexpr int kTCH = 64;        // scan t-chunk
}

__device__ __forceinline__ float siluf_(float v) {
  return v / (1.f + expf(-v));
}
__device__ __forceinline__ float softplusf_(float v) {
  return (v > 20.f) ? v : log1pf(expf(v));
}

template <int CTRL>
__device__ __forceinline__ float ror_add_(float v) {
  int m = __builtin_amdgcn_update_dpp(0, __float_as_int(v), CTRL, 0xf, 0xf, false);
  return v + __int_as_float(m);
}

// ---------------- K1: depthwise conv1d, pad=3, KW=4 -> xc [B, Lc, D] ------
__global__ __launch_bounds__(256) void conv_kernel(
    const float* __restrict__ x, const float* __restrict__ cw,
    const float* __restrict__ cb, float* __restrict__ xc) {
  int idx = blockIdx.x * blockDim.x + threadIdx.x;
  const int D4 = kD / 4;
  if (idx >= kB * kLc * D4) return;
  int d4 = idx % D4;
  int bt = idx / D4;
  int t = bt % kLc;
  int b = bt / kLc;
  int d = d4 * 4;

  float4 w0 = *(const float4*)(cw + (size_t)(d + 0) * 4);
  float4 w1 = *(const float4*)(cw + (size_t)(d + 1) * 4);
  float4 w2 = *(const float4*)(cw + (size_t)(d + 2) * 4);
  float4 w3 = *(const float4*)(cw + (size_t)(d + 3) * 4);
  float4 acc = *(const float4*)(cb + d);

#pragma unroll
  for (int k = 0; k < 4; ++k) {
    int ti = t + k - 3;
    if (ti >= 0 && ti < kL) {
      float4 xv = *(const float4*)(x + ((size_t)b * kL + ti) * kD + d);
      acc.x = fmaf(((const float*)&w0)[k], xv.x, acc.x);
      acc.y = fmaf(((const float*)&w1)[k], xv.y, acc.y);
      acc.z = fmaf(((const float*)&w2)[k], xv.z, acc.z);
      acc.w = fmaf(((const float*)&w3)[k], xv.w, acc.w);
    }
  }
  *(float4*)(xc + (size_t)bt * kD + d) = acc;
}

// ---------------- K2: projections + selective-param epilogue --------------
// GEMM [kM x 1024] * [1024 x 196]; block = 32 rows, thread = 1 output col.
__global__ __launch_bounds__(256) void proj_kernel(
    const float* __restrict__ xc,
    const float* __restrict__ W_U, const float* __restrict__ W_B,
    const float* __restrict__ b_B, const float* __restrict__ W_C,
    const float* __restrict__ b_C, const float* __restrict__ W_d1,
    const float* __restrict__ b_d1, const float* __restrict__ W_d2,
    const float* __restrict__ b_d2, const float* __restrict__ a_hat,
    float* __restrict__ At, float* __restrict__ Bt, float* __restrict__ Ct) {
  __shared__ __align__(16) float xcl[kMT][36];   // [row][k], +pad
  __shared__ __align__(16) float wl[256][33];    // [col][k], +1 pad: conflict-free
  __shared__ __align__(16) float raw[kMT][200];

  int tid = threadIdx.x;
  int r0 = blockIdx.x * kMT;
  int lrow = tid >> 3, lkq = tid & 7;

  float acc[kMT];
#pragma unroll
  for (int i = 0; i < kMT; ++i) acc[i] = 0.f;

  for (int kb = 0; kb < kD; kb += 32) {
    __syncthreads();
    // stage xc tile [32 rows][32 k]
    {
      int gr = r0 + lrow;
      float4 v = make_float4(0.f, 0.f, 0.f, 0.f);
      if (gr < kM) v = *(const float4*)(xc + (size_t)gr * kD + kb + lkq * 4);
      *(float4*)&xcl[lrow][lkq * 4] = v;
    }
    // stage W tile [256 cols (196 real, rest zero)][32 k]
#pragma unroll
    for (int p = 0; p < 8; ++p) {
      int wr = p * 32 + lrow;
      float4 v = make_float4(0.f, 0.f, 0.f, 0.f);
      if (wr < kNC) {
        const float* src;
        if (wr < 64)       src = W_U + (size_t)wr * kD;
        else if (wr < 128) src = W_B + (size_t)(wr - 64) * kD;
        else if (wr < 192) src = W_C + (size_t)(wr - 128) * kD;
        else               src = W_d1 + (size_t)(wr - 192) * kD;
        v = *(const float4*)(src + kb + lkq * 4);
      }
      wl[wr][lkq * 4 + 0] = v.x;
      wl[wr][lkq * 4 + 1] = v.y;
      wl[wr][lkq * 4 + 2] = v.z;
      wl[wr][lkq * 4 + 3] = v.w;
    }
    __syncthreads();
#pragma unroll
    for (int k = 0; k < 32; k += 4) {
      float w0 = wl[tid][k + 0];
      float w1 = wl[tid][k + 1];
      float w2 = wl[tid][k + 2];
      float w3 = wl[tid][k + 3];
#pragma unroll
      for (int row = 0; row < kMT; ++row) {
        float4 xv = *(const float4*)&xcl[row][k];  // wave-uniform: broadcast
        acc[row] = fmaf(w0, xv.x, acc[row]);
        acc[row] = fmaf(w1, xv.y, acc[row]);
        acc[row] = fmaf(w2, xv.z, acc[row]);
        acc[row] = fmaf(w3, xv.w, acc[row]);
      }
    }
  }
  __syncthreads();
  if (tid < 200) {
#pragma unroll
    for (int row = 0; row < kMT; ++row) raw[row][tid] = acc[row];
  }
  __syncthreads();

  // recombine: thread -> (s = tid&63, row group = tid>>6)
  int s = tid & 63;
  int rg = tid >> 6;
  float bBs = b_B[s];
  float bCs = b_C[s];
  float nEA = -expf(a_hat[s]);
  float wd20 = W_d2[0], wd21 = W_d2[1], wd22 = W_d2[2], wd23 = W_d2[3];
  float bd2 = b_d2[0];
  float bd10 = b_d1[0], bd11 = b_d1[1], bd12 = b_d1[2], bd13 = b_d1[3];

  for (int row = rg; row < kMT; row += 4) {
    int gr = r0 + row;
    if (gr >= kM) break;
    float u  = raw[row][s];
    float ub = raw[row][64 + s];
    float uc = raw[row][128 + s];
    float f0 = siluf_(raw[row][192] + bd10);
    float f1 = siluf_(raw[row][193] + bd11);
    float f2 = siluf_(raw[row][194] + bd12);
    float f3 = siluf_(raw[row][195] + bd13);
    float z = f0 * wd20 + f1 * wd21 + f2 * wd22 + f3 * wd23 + bd2;
    float delta = softplusf_(z);
    size_t o = (size_t)gr * kS + s;
    At[o] = expf(delta * nEA);
    Bt[o] = (ub + bBs) * u;
    Ct[o] = uc + bCs;
  }
}

// ---------------- K3: selective scan ------------------------------------
// block = (b, 16-channel slab); thread = (d_local = tid>>4, s-quad = tid&15).
__global__ __launch_bounds__(256) void scan_kernel(
    const float* __restrict__ At, const float* __restrict__ Bt,
    const float* __restrict__ Ct, const float* __restrict__ xc,
    const float* __restrict__ D_skip, float* __restrict__ out) {
  __shared__ __align__(16) float Al[kTCH][kS];
  __shared__ __align__(16) float Bl[kTCH][kS];
  __shared__ __align__(16) float Cl[kTCH][kS];
  __shared__ __align__(16) float xcl[kTCH][16];
  __shared__ __align__(16) float yl[kTCH][16];

  int tid = threadIdx.x;
  int b = blockIdx.x >> 6;
  int d0 = (blockIdx.x & 63) << 4;
  int dl = tid >> 4;   // 0..15 channel within slab
  int sq = tid & 15;   // s-quad index; lanes of a 16-row share dl
  int s0 = sq * 4;

  float h0 = 0.f, h1 = 0.f, h2 = 0.f, h3 = 0.f;
  float ds = D_skip[d0 + dl];

  const size_t baseS = (size_t)b * kLc * kS;
  const size_t baseD = (size_t)b * kLc * kD;

  for (int tc = 0; tc < kLc; tc += kTCH) {
    int clen = min(kTCH, kLc - tc);
    __syncthreads();
    {
      int nv = clen * (kS / 4);
      const float4* gA = (const float4*)(At + baseS + (size_t)tc * kS);
      const float4* gB = (const float4*)(Bt + baseS + (size_t)tc * kS);
      const float4* gC = (const float4*)(Ct + baseS + (size_t)tc * kS);
      for (int i = tid; i < nv; i += 256) {
        ((float4*)Al)[i] = gA[i];
        ((float4*)Bl)[i] = gB[i];
        ((float4*)Cl)[i] = gC[i];
      }
      for (int i = tid; i < clen * 16; i += 256) {
        int tt = i >> 4, dd = i & 15;
        xcl[tt][dd] = xc[baseD + (size_t)(tc + tt) * kD + d0 + dd];
      }
    }
    __syncthreads();

    for (int tt = 0; tt < clen; ++tt) {
      float xcv = xcl[tt][dl];
      float4 a  = *(const float4*)&Al[tt][s0];
      float4 bv = *(const float4*)&Bl[tt][s0];
      float4 c  = *(const float4*)&Cl[tt][s0];
      h0 = fmaf(a.x, h0, bv.x * xcv);
      h1 = fmaf(a.y, h1, bv.y * xcv);
      h2 = fmaf(a.z, h2, bv.z * xcv);
      h3 = fmaf(a.w, h3, bv.w * xcv);
      float dot = fmaf(c.x, h0, fmaf(c.y, h1, fmaf(c.z, h2, c.w * h3)));
      // rotate-allreduce across the 16 lanes of this row (same dl)
      dot = ror_add_<0x128>(dot);  // row_ror:8
      dot = ror_add_<0x124>(dot);  // row_ror:4
      dot = ror_add_<0x122>(dot);  // row_ror:2
      dot = ror_add_<0x121>(dot);  // row_ror:1
      if (sq == 0) yl[tt][dl] = fmaf(ds, xcv, dot);
    }
    __syncthreads();

    for (int i = tid; i < clen * 16; i += 256) {
      int tt = i >> 4, dd = i & 15;
      out[baseD + (size_t)(tc + tt) * kD + d0 + dd] = yl[tt][dd];
    }
  }
}

extern "C" void kernel_launch(void* const* d_in, const int* in_sizes, int n_in,
                              void* d_out, int out_size, void* d_ws, size_t ws_size,
                              hipStream_t stream) {
  const float* x      = (const float*)d_in[0];
  const float* a_hat  = (const float*)d_in[1];
  const float* W_U    = (const float*)d_in[2];
  const float* W_B    = (const float*)d_in[3];
  const float* b_B    = (const float*)d_in[4];
  const float* W_C    = (const float*)d_in[5];
  const float* b_C    = (const float*)d_in[6];
  const float* W_d1   = (const float*)d_in[7];
  const float* b_d1   = (const float*)d_in[8];
  const float* W_d2   = (const float*)d_in[9];
  const float* b_d2   = (const float*)d_in[10];
  const float* D_skip = (const float*)d_in[11];
  const float* conv_w = (const float*)d_in[12];
  const float* conv_b = (const float*)d_in[13];
  float* out = (float*)d_out;

  float* xc = (float*)d_ws;
  float* At = xc + (size_t)kB * kLc * kD;
  float* Bt = At + (size_t)kB * kLc * kS;
  float* Ct = Bt + (size_t)kB * kLc * kS;

  int convThreads = kB * kLc * (kD / 4);
  conv_kernel<<<(convThreads + 255) / 256, 256, 0, stream>>>(x, conv_w, conv_b, xc);

  proj_kernel<<<(kM + kMT - 1) / kMT, 256, 0, stream>>>(
      xc, W_U, W_B, b_B, W_C, b_C, W_d1, b_d1, W_d2, b_d2, a_hat, At, Bt, Ct);

  scan_kernel<<<kB * 64, 256, 0, stream>>>(At, Bt, Ct, xc, D_skip, out);
}

// Round 2
// 453.746 us; speedup vs baseline: 2.0790x; 2.0790x over previous
//
#include <hip/hip_runtime.h>
#include <hip/hip_bf16.h>

namespace {
constexpr int kB   = 4;
constexpr int kL   = 2048;
constexpr int kLc  = 2051;   // L + 3
constexpr int kD   = 1024;
constexpr int kS   = 64;
constexpr int kM   = kB * kLc;  // 8204 flattened (b,t) rows
constexpr int kNR  = 256;       // raw row stride (196 real cols, padded)
constexpr int kTCH = 64;        // scan t-chunk
}

__device__ __forceinline__ float siluf_(float v) {
  return v / (1.f + expf(-v));
}
__device__ __forceinline__ float softplusf_(float v) {
  return (v > 20.f) ? v : log1pf(expf(v));
}

template <int CTRL>
__device__ __forceinline__ float ror_add_(float v) {
  int m = __builtin_amdgcn_update_dpp(0, __float_as_int(v), CTRL, 0xf, 0xf, false);
  return v + __int_as_float(m);
}

// ---------------- K1: depthwise conv1d, pad=3, KW=4 -> xc [B, Lc, D] ------
__global__ __launch_bounds__(256) void conv_kernel(
    const float* __restrict__ x, const float* __restrict__ cw,
    const float* __restrict__ cb, float* __restrict__ xc) {
  int idx = blockIdx.x * blockDim.x + threadIdx.x;
  const int D4 = kD / 4;
  if (idx >= kB * kLc * D4) return;
  int d4 = idx % D4;
  int bt = idx / D4;
  int t = bt % kLc;
  int b = bt / kLc;
  int d = d4 * 4;

  float4 w0 = *(const float4*)(cw + (size_t)(d + 0) * 4);
  float4 w1 = *(const float4*)(cw + (size_t)(d + 1) * 4);
  float4 w2 = *(const float4*)(cw + (size_t)(d + 2) * 4);
  float4 w3 = *(const float4*)(cw + (size_t)(d + 3) * 4);
  float4 acc = *(const float4*)(cb + d);

#pragma unroll
  for (int k = 0; k < 4; ++k) {
    int ti = t + k - 3;
    if (ti >= 0 && ti < kL) {
      float4 xv = *(const float4*)(x + ((size_t)b * kL + ti) * kD + d);
      acc.x = fmaf(((const float*)&w0)[k], xv.x, acc.x);
      acc.y = fmaf(((const float*)&w1)[k], xv.y, acc.y);
      acc.z = fmaf(((const float*)&w2)[k], xv.z, acc.z);
      acc.w = fmaf(((const float*)&w3)[k], xv.w, acc.w);
    }
  }
  *(float4*)(xc + (size_t)bt * kD + d) = acc;
}

// ---------------- K2a: raw = xc @ Wcat^T  (fp32 tiled GEMM) ---------------
// C[kM x 256(196 real)] ; block tile 64x64, micro 4x4, K-chunk 32.
// Wcat rows: [0,64)=W_U, [64,128)=W_B, [128,192)=W_C, [192,196)=W_d1, rest 0.
__global__ __launch_bounds__(256) void gemm_kernel(
    const float* __restrict__ xc,
    const float* __restrict__ W_U, const float* __restrict__ W_B,
    const float* __restrict__ W_C, const float* __restrict__ W_d1,
    float* __restrict__ raw) {
  __shared__ __align__(16) float xcl[32][68];  // [k][m], 68*4B = 16B-aligned rows
  __shared__ __align__(16) float wl[32][68];   // [k][n]

  const int tid = threadIdx.x;
  const int m0 = blockIdx.x * 64;
  const int n0 = blockIdx.y * 64;
  const int tm = tid >> 4;   // 0..15 -> rows tm*4..tm*4+3
  const int tn = tid & 15;   // 0..15 -> cols tn*4..tn*4+3

  // staging identities: idx = tid + p*256 ; m/n = idx>>3, kq = idx&7
  const int sm = tid >> 3;       // 0..31 (p adds +32)
  const int skq = tid & 7;

  // per-thread W source rows (resolved once; k-offset added per chunk)
  const float* wsrc[2];
  bool wval[2];
#pragma unroll
  for (int p = 0; p < 2; ++p) {
    int n = sm + p * 32;
    int col = n0 + n;
    const float* src = nullptr;
    if (col < 64)       src = W_U + (size_t)col * kD;
    else if (col < 128) src = W_B + (size_t)(col - 64) * kD;
    else if (col < 192) src = W_C + (size_t)(col - 128) * kD;
    else if (col < 196) src = W_d1 + (size_t)(col - 192) * kD;
    wsrc[p] = src;
    wval[p] = (src != nullptr);
  }
  const float* xsrc[2];
  bool xval[2];
#pragma unroll
  for (int p = 0; p < 2; ++p) {
    int m = sm + p * 32;
    int row = m0 + m;
    xval[p] = (row < kM);
    xsrc[p] = xc + (size_t)row * kD;
  }

  float acc[4][4];
#pragma unroll
  for (int i = 0; i < 4; ++i)
#pragma unroll
    for (int j = 0; j < 4; ++j) acc[i][j] = 0.f;

  for (int kb = 0; kb < kD; kb += 32) {
    __syncthreads();
#pragma unroll
    for (int p = 0; p < 2; ++p) {
      int m = sm + p * 32;
      float4 xv = make_float4(0.f, 0.f, 0.f, 0.f);
      float4 wv = make_float4(0.f, 0.f, 0.f, 0.f);
      if (xval[p]) xv = *(const float4*)(xsrc[p] + kb + skq * 4);
      if (wval[p]) wv = *(const float4*)(wsrc[p] + kb + skq * 4);
      xcl[skq * 4 + 0][m] = xv.x;
      xcl[skq * 4 + 1][m] = xv.y;
      xcl[skq * 4 + 2][m] = xv.z;
      xcl[skq * 4 + 3][m] = xv.w;
      wl[skq * 4 + 0][m] = wv.x;
      wl[skq * 4 + 1][m] = wv.y;
      wl[skq * 4 + 2][m] = wv.z;
      wl[skq * 4 + 3][m] = wv.w;
    }
    __syncthreads();
#pragma unroll
    for (int k = 0; k < 32; ++k) {
      float4 a = *(const float4*)&xcl[k][tm * 4];
      float4 w = *(const float4*)&wl[k][tn * 4];
      const float* ap = (const float*)&a;
      const float* wp = (const float*)&w;
#pragma unroll
      for (int i = 0; i < 4; ++i)
#pragma unroll
        for (int j = 0; j < 4; ++j) acc[i][j] = fmaf(ap[i], wp[j], acc[i][j]);
    }
  }

#pragma unroll
  for (int i = 0; i < 4; ++i) {
    int row = m0 + tm * 4 + i;
    if (row < kM) {
      *(float4*)(raw + (size_t)row * kNR + n0 + tn * 4) =
          make_float4(acc[i][0], acc[i][1], acc[i][2], acc[i][3]);
    }
  }
}

// ---------------- K2b: epilogue -> At, Bt, Ct ----------------------------
__global__ __launch_bounds__(256) void epi_kernel(
    const float* __restrict__ raw,
    const float* __restrict__ b_B, const float* __restrict__ b_C,
    const float* __restrict__ b_d1, const float* __restrict__ W_d2,
    const float* __restrict__ b_d2, const float* __restrict__ a_hat,
    float* __restrict__ At, float* __restrict__ Bt, float* __restrict__ Ct) {
  int idx = blockIdx.x * blockDim.x + threadIdx.x;
  if (idx >= kM * kS) return;
  int s = idx & 63;
  int row = idx >> 6;
  const float* r = raw + (size_t)row * kNR;

  float u  = r[s];
  float rb = r[64 + s] + b_B[s];
  float rc = r[128 + s] + b_C[s];
  float f0 = siluf_(r[192] + b_d1[0]);
  float f1 = siluf_(r[193] + b_d1[1]);
  float f2 = siluf_(r[194] + b_d1[2]);
  float f3 = siluf_(r[195] + b_d1[3]);
  float z = fmaf(f0, W_d2[0], fmaf(f1, W_d2[1], fmaf(f2, W_d2[2], fmaf(f3, W_d2[3], b_d2[0]))));
  float delta = softplusf_(z);
  size_t o = (size_t)row * kS + s;
  At[o] = expf(delta * -expf(a_hat[s]));
  Bt[o] = rb * u;
  Ct[o] = rc;
}

// ---------------- K3: selective scan ------------------------------------
// block = (b, 16-channel slab); thread = (d_local = tid>>4, s-quad = tid&15).
__global__ __launch_bounds__(256) void scan_kernel(
    const float* __restrict__ At, const float* __restrict__ Bt,
    const float* __restrict__ Ct, const float* __restrict__ xc,
    const float* __restrict__ D_skip, float* __restrict__ out) {
  __shared__ __align__(16) float Al[kTCH][kS];
  __shared__ __align__(16) float Bl[kTCH][kS];
  __shared__ __align__(16) float Cl[kTCH][kS];
  __shared__ __align__(16) float xcl[kTCH][16];
  __shared__ __align__(16) float yl[kTCH][16];

  int tid = threadIdx.x;
  int b = blockIdx.x >> 6;
  int d0 = (blockIdx.x & 63) << 4;
  int dl = tid >> 4;   // 0..15 channel within slab
  int sq = tid & 15;   // s-quad index
  int s0 = sq * 4;

  float h0 = 0.f, h1 = 0.f, h2 = 0.f, h3 = 0.f;
  float ds = D_skip[d0 + dl];

  const size_t baseS = (size_t)b * kLc * kS;
  const size_t baseD = (size_t)b * kLc * kD;

  for (int tc = 0; tc < kLc; tc += kTCH) {
    int clen = min(kTCH, kLc - tc);
    __syncthreads();
    {
      int nv = clen * (kS / 4);
      const float4* gA = (const float4*)(At + baseS + (size_t)tc * kS);
      const float4* gB = (const float4*)(Bt + baseS + (size_t)tc * kS);
      const float4* gC = (const float4*)(Ct + baseS + (size_t)tc * kS);
      for (int i = tid; i < nv; i += 256) {
        ((float4*)Al)[i] = gA[i];
        ((float4*)Bl)[i] = gB[i];
        ((float4*)Cl)[i] = gC[i];
      }
      for (int i = tid; i < clen * 16; i += 256) {
        int tt = i >> 4, dd = i & 15;
        xcl[tt][dd] = xc[baseD + (size_t)(tc + tt) * kD + d0 + dd];
      }
    }
    __syncthreads();

    for (int tt = 0; tt < clen; ++tt) {
      float xcv = xcl[tt][dl];
      float4 a  = *(const float4*)&Al[tt][s0];
      float4 bv = *(const float4*)&Bl[tt][s0];
      float4 c  = *(const float4*)&Cl[tt][s0];
      h0 = fmaf(a.x, h0, bv.x * xcv);
      h1 = fmaf(a.y, h1, bv.y * xcv);
      h2 = fmaf(a.z, h2, bv.z * xcv);
      h3 = fmaf(a.w, h3, bv.w * xcv);
      float dot = fmaf(c.x, h0, fmaf(c.y, h1, fmaf(c.z, h2, c.w * h3)));
      dot = ror_add_<0x128>(dot);  // row_ror:8
      dot = ror_add_<0x124>(dot);  // row_ror:4
      dot = ror_add_<0x122>(dot);  // row_ror:2
      dot = ror_add_<0x121>(dot);  // row_ror:1
      if (sq == 0) yl[tt][dl] = fmaf(ds, xcv, dot);
    }
    __syncthreads();

    for (int i = tid; i < clen * 16; i += 256) {
      int tt = i >> 4, dd = i & 15;
      out[baseD + (size_t)(tc + tt) * kD + d0 + dd] = yl[tt][dd];
    }
  }
}

extern "C" void kernel_launch(void* const* d_in, const int* in_sizes, int n_in,
                              void* d_out, int out_size, void* d_ws, size_t ws_size,
                              hipStream_t stream) {
  const float* x      = (const float*)d_in[0];
  const float* a_hat  = (const float*)d_in[1];
  const float* W_U    = (const float*)d_in[2];
  const float* W_B    = (const float*)d_in[3];
  const float* b_B    = (const float*)d_in[4];
  const float* W_C    = (const float*)d_in[5];
  const float* b_C    = (const float*)d_in[6];
  const float* W_d1   = (const float*)d_in[7];
  const float* b_d1   = (const float*)d_in[8];
  const float* W_d2   = (const float*)d_in[9];
  const float* b_d2   = (const float*)d_in[10];
  const float* D_skip = (const float*)d_in[11];
  const float* conv_w = (const float*)d_in[12];
  const float* conv_b = (const float*)d_in[13];
  float* out = (float*)d_out;

  float* xc  = (float*)d_ws;                       // kM * kD
  float* raw = xc + (size_t)kM * kD;               // kM * kNR
  float* At  = raw + (size_t)kM * kNR;             // kM * kS
  float* Bt  = At + (size_t)kM * kS;
  float* Ct  = Bt + (size_t)kM * kS;

  int convThreads = kB * kLc * (kD / 4);
  conv_kernel<<<(convThreads + 255) / 256, 256, 0, stream>>>(x, conv_w, conv_b, xc);

  dim3 ggrid((kM + 63) / 64, 4);
  gemm_kernel<<<ggrid, 256, 0, stream>>>(xc, W_U, W_B, W_C, W_d1, raw);

  epi_kernel<<<(kM * kS + 255) / 256, 256, 0, stream>>>(
      raw, b_B, b_C, b_d1, W_d2, b_d2, a_hat, At, Bt, Ct);

  scan_kernel<<<kB * 64, 256, 0, stream>>>(At, Bt, Ct, xc, D_skip, out);
}

// Round 3
// 274.252 us; speedup vs baseline: 3.4396x; 1.6545x over previous
//
#include <hip/hip_runtime.h>
#include <hip/hip_bf16.h>

namespace {
constexpr int kB   = 4;
constexpr int kL   = 2048;
constexpr int kLc  = 2051;   // L + 3
constexpr int kD   = 1024;
constexpr int kS   = 64;
constexpr int kM   = kB * kLc;  // 8204 flattened (b,t) rows
constexpr int kNR  = 256;       // raw row stride (196 real cols, padded)
constexpr int kQ   = 64;        // scan time-chunk length
constexpr int kTC  = (kLc + kQ - 1) / kQ;  // 33 chunks per batch
}

__device__ __forceinline__ float siluf_(float v) {
  return v / (1.f + expf(-v));
}
__device__ __forceinline__ float softplusf_(float v) {
  return (v > 20.f) ? v : log1pf(expf(v));
}

template <int CTRL>
__device__ __forceinline__ float ror_add_(float v) {
  int m = __builtin_amdgcn_update_dpp(0, __float_as_int(v), CTRL, 0xf, 0xf, false);
  return v + __int_as_float(m);
}

// ---------------- K1: depthwise conv1d, pad=3, KW=4 -> xc [B, Lc, D] ------
__global__ __launch_bounds__(256) void conv_kernel(
    const float* __restrict__ x, const float* __restrict__ cw,
    const float* __restrict__ cb, float* __restrict__ xc) {
  int idx = blockIdx.x * blockDim.x + threadIdx.x;
  const int D4 = kD / 4;
  if (idx >= kB * kLc * D4) return;
  int d4 = idx % D4;
  int bt = idx / D4;
  int t = bt % kLc;
  int b = bt / kLc;
  int d = d4 * 4;

  float4 w0 = *(const float4*)(cw + (size_t)(d + 0) * 4);
  float4 w1 = *(const float4*)(cw + (size_t)(d + 1) * 4);
  float4 w2 = *(const float4*)(cw + (size_t)(d + 2) * 4);
  float4 w3 = *(const float4*)(cw + (size_t)(d + 3) * 4);
  float4 acc = *(const float4*)(cb + d);

#pragma unroll
  for (int k = 0; k < 4; ++k) {
    int ti = t + k - 3;
    if (ti >= 0 && ti < kL) {
      float4 xv = *(const float4*)(x + ((size_t)b * kL + ti) * kD + d);
      acc.x = fmaf(((const float*)&w0)[k], xv.x, acc.x);
      acc.y = fmaf(((const float*)&w1)[k], xv.y, acc.y);
      acc.z = fmaf(((const float*)&w2)[k], xv.z, acc.z);
      acc.w = fmaf(((const float*)&w3)[k], xv.w, acc.w);
    }
  }
  *(float4*)(xc + (size_t)bt * kD + d) = acc;
}

// ---------------- K2a: raw = xc @ Wcat^T  (fp32 tiled GEMM) ---------------
__global__ __launch_bounds__(256) void gemm_kernel(
    const float* __restrict__ xc,
    const float* __restrict__ W_U, const float* __restrict__ W_B,
    const float* __restrict__ W_C, const float* __restrict__ W_d1,
    float* __restrict__ raw) {
  __shared__ __align__(16) float xcl[32][68];
  __shared__ __align__(16) float wl[32][68];

  const int tid = threadIdx.x;
  const int m0 = blockIdx.x * 64;
  const int n0 = blockIdx.y * 64;
  const int tm = tid >> 4;
  const int tn = tid & 15;
  const int sm = tid >> 3;
  const int skq = tid & 7;

  const float* wsrc[2];
  bool wval[2];
#pragma unroll
  for (int p = 0; p < 2; ++p) {
    int col = n0 + sm + p * 32;
    const float* src = nullptr;
    if (col < 64)       src = W_U + (size_t)col * kD;
    else if (col < 128) src = W_B + (size_t)(col - 64) * kD;
    else if (col < 192) src = W_C + (size_t)(col - 128) * kD;
    else if (col < 196) src = W_d1 + (size_t)(col - 192) * kD;
    wsrc[p] = src;
    wval[p] = (src != nullptr);
  }
  const float* xsrc[2];
  bool xval[2];
#pragma unroll
  for (int p = 0; p < 2; ++p) {
    int row = m0 + sm + p * 32;
    xval[p] = (row < kM);
    xsrc[p] = xc + (size_t)row * kD;
  }

  float acc[4][4];
#pragma unroll
  for (int i = 0; i < 4; ++i)
#pragma unroll
    for (int j = 0; j < 4; ++j) acc[i][j] = 0.f;

  for (int kb = 0; kb < kD; kb += 32) {
    __syncthreads();
#pragma unroll
    for (int p = 0; p < 2; ++p) {
      int m = sm + p * 32;
      float4 xv = make_float4(0.f, 0.f, 0.f, 0.f);
      float4 wv = make_float4(0.f, 0.f, 0.f, 0.f);
      if (xval[p]) xv = *(const float4*)(xsrc[p] + kb + skq * 4);
      if (wval[p]) wv = *(const float4*)(wsrc[p] + kb + skq * 4);
      xcl[skq * 4 + 0][m] = xv.x;
      xcl[skq * 4 + 1][m] = xv.y;
      xcl[skq * 4 + 2][m] = xv.z;
      xcl[skq * 4 + 3][m] = xv.w;
      wl[skq * 4 + 0][m] = wv.x;
      wl[skq * 4 + 1][m] = wv.y;
      wl[skq * 4 + 2][m] = wv.z;
      wl[skq * 4 + 3][m] = wv.w;
    }
    __syncthreads();
#pragma unroll
    for (int k = 0; k < 32; ++k) {
      float4 a = *(const float4*)&xcl[k][tm * 4];
      float4 w = *(const float4*)&wl[k][tn * 4];
      const float* ap = (const float*)&a;
      const float* wp = (const float*)&w;
#pragma unroll
      for (int i = 0; i < 4; ++i)
#pragma unroll
        for (int j = 0; j < 4; ++j) acc[i][j] = fmaf(ap[i], wp[j], acc[i][j]);
    }
  }

#pragma unroll
  for (int i = 0; i < 4; ++i) {
    int row = m0 + tm * 4 + i;
    if (row < kM) {
      *(float4*)(raw + (size_t)row * kNR + n0 + tn * 4) =
          make_float4(acc[i][0], acc[i][1], acc[i][2], acc[i][3]);
    }
  }
}

// ---------------- K2b: epilogue -> At, Bt, Ct ----------------------------
__global__ __launch_bounds__(256) void epi_kernel(
    const float* __restrict__ raw,
    const float* __restrict__ b_B, const float* __restrict__ b_C,
    const float* __restrict__ b_d1, const float* __restrict__ W_d2,
    const float* __restrict__ b_d2, const float* __restrict__ a_hat,
    float* __restrict__ At, float* __restrict__ Bt, float* __restrict__ Ct) {
  int idx = blockIdx.x * blockDim.x + threadIdx.x;
  if (idx >= kM * kS) return;
  int s = idx & 63;
  int row = idx >> 6;
  const float* r = raw + (size_t)row * kNR;

  float u  = r[s];
  float rb = r[64 + s] + b_B[s];
  float rc = r[128 + s] + b_C[s];
  float f0 = siluf_(r[192] + b_d1[0]);
  float f1 = siluf_(r[193] + b_d1[1]);
  float f2 = siluf_(r[194] + b_d1[2]);
  float f3 = siluf_(r[195] + b_d1[3]);
  float z = fmaf(f0, W_d2[0], fmaf(f1, W_d2[1], fmaf(f2, W_d2[2], fmaf(f3, W_d2[3], b_d2[0]))));
  float delta = softplusf_(z);
  size_t o = (size_t)row * kS + s;
  At[o] = expf(delta * -expf(a_hat[s]));
  Bt[o] = rb * u;
  Ct[o] = rc;
}

// ---------------- K3a: per-chunk backward cumprod -------------------------
// Bpre[bc, tau, s] = (prod_{j>tau} A[j,s]) * B[tau,s];  dec[bc,s] = prod_all A.
__global__ __launch_bounds__(64) void prep_kernel(
    const float* __restrict__ At, const float* __restrict__ Bt,
    float* __restrict__ Bpre, float* __restrict__ dec) {
  __shared__ __align__(16) float Aloc[kQ][kS];
  __shared__ __align__(16) float Bloc[kQ][kS];
  int tid = threadIdx.x;  // 64
  int bc = blockIdx.x;
  int b = bc / kTC, c = bc % kTC;
  int t0 = c * kQ;
  int clen = min(kQ, kLc - t0);
  size_t baseS = ((size_t)b * kLc + t0) * kS;

  for (int i = tid; i < kQ * (kS / 4); i += 64) {
    int tt = i >> 4;
    int sq = i & 15;
    float4 a = make_float4(1.f, 1.f, 1.f, 1.f);
    float4 bv = make_float4(0.f, 0.f, 0.f, 0.f);
    if (tt < clen) {
      a  = *(const float4*)(At + baseS + (size_t)tt * kS + sq * 4);
      bv = *(const float4*)(Bt + baseS + (size_t)tt * kS + sq * 4);
    }
    *(float4*)&Aloc[tt][sq * 4] = a;
    *(float4*)&Bloc[tt][sq * 4] = bv;
  }
  __syncthreads();
  int s = tid;
  float E = 1.f;
  for (int tt = kQ - 1; tt >= 0; --tt) {
    Bpre[((size_t)bc * kQ + tt) * kS + s] = E * Bloc[tt][s];
    E *= Aloc[tt][s];
  }
  dec[(size_t)bc * kS + s] = E;
}

// ---------------- K3b: partial end-state GEMM -----------------------------
// Sc[bc, s, d] = sum_tau Bpre[bc,tau,s] * xc[b, t0+tau, d]
__global__ __launch_bounds__(256) void pstate_kernel(
    const float* __restrict__ Bpre, const float* __restrict__ xc,
    float* __restrict__ Sc) {
  __shared__ __align__(16) float bpl[16][68];
  __shared__ __align__(16) float xl[16][68];
  int tid = threadIdx.x;
  int bc = blockIdx.y;
  int b = bc / kTC, c = bc % kTC;
  int d0 = blockIdx.x * 64;
  int tm = tid >> 4, tn = tid & 15;
  int srow = tid >> 4, scol = tid & 15;
  int t0 = c * kQ;

  float acc[4][4];
#pragma unroll
  for (int i = 0; i < 4; ++i)
#pragma unroll
    for (int j = 0; j < 4; ++j) acc[i][j] = 0.f;

  for (int kb = 0; kb < kQ; kb += 16) {
    __syncthreads();
    {
      float4 bv = *(const float4*)(Bpre + ((size_t)bc * kQ + kb + srow) * kS + scol * 4);
      int gt = t0 + kb + srow;
      if (gt > kLc - 1) gt = kLc - 1;  // clamp; Bpre is 0 there
      float4 xv = *(const float4*)(xc + ((size_t)b * kLc + gt) * kD + d0 + scol * 4);
      *(float4*)&bpl[srow][scol * 4] = bv;
      *(float4*)&xl[srow][scol * 4] = xv;
    }
    __syncthreads();
#pragma unroll
    for (int k = 0; k < 16; ++k) {
      float4 a = *(const float4*)&bpl[k][tm * 4];
      float4 w = *(const float4*)&xl[k][tn * 4];
      const float* ap = (const float*)&a;
      const float* wp = (const float*)&w;
#pragma unroll
      for (int i = 0; i < 4; ++i)
#pragma unroll
        for (int j = 0; j < 4; ++j) acc[i][j] = fmaf(ap[i], wp[j], acc[i][j]);
    }
  }
#pragma unroll
  for (int i = 0; i < 4; ++i) {
    *(float4*)(Sc + ((size_t)bc * kS + tm * 4 + i) * kD + d0 + tn * 4) =
        make_float4(acc[i][0], acc[i][1], acc[i][2], acc[i][3]);
  }
}

// ---------------- K3c: cross-chunk state scan (in-place Sc -> H_before) ---
__global__ __launch_bounds__(256) void chscan_kernel(
    const float* __restrict__ dec, float* __restrict__ Sc) {
  int bs = blockIdx.x;           // b*kS + s
  int dq = threadIdx.x;          // 0..255 -> d quad
  int b = bs >> 6, s = bs & 63;
  float4 run = make_float4(0.f, 0.f, 0.f, 0.f);
  for (int c = 0; c < kTC; ++c) {
    size_t off = ((size_t)(b * kTC + c) * kS + s) * kD + dq * 4;
    float4 tmp = *(const float4*)(Sc + off);
    *(float4*)(Sc + off) = run;  // H_before[c]
    float dc = dec[(size_t)(b * kTC + c) * kS + s];
    run.x = fmaf(dc, run.x, tmp.x);
    run.y = fmaf(dc, run.y, tmp.y);
    run.z = fmaf(dc, run.z, tmp.z);
    run.w = fmaf(dc, run.w, tmp.w);
  }
}

// ---------------- K3d: final chunked scan ---------------------------------
// block = (b, chunk c, 16-channel slab); serial over <=64 steps in chunk.
__global__ __launch_bounds__(256) void final_kernel(
    const float* __restrict__ At, const float* __restrict__ Bt,
    const float* __restrict__ Ct, const float* __restrict__ xc,
    const float* __restrict__ Hst, const float* __restrict__ D_skip,
    float* __restrict__ out) {
  __shared__ __align__(16) float Al[32][kS];
  __shared__ __align__(16) float Bl[32][kS];
  __shared__ __align__(16) float Cl[32][kS];
  __shared__ __align__(16) float xcl[kQ][16];
  __shared__ __align__(16) float yl[kQ][16];

  int tid = threadIdx.x;
  int slab = blockIdx.x & 63;
  int bc = blockIdx.x >> 6;      // b*kTC + c
  int b = bc / kTC, c = bc % kTC;
  int d0 = slab << 4;
  int dl = tid >> 4, sq = tid & 15, s0 = sq * 4;
  int t0 = c * kQ;
  int clen = min(kQ, kLc - t0);

  float h0, h1, h2, h3;
  {
    size_t hb = (size_t)bc * kS * kD + d0 + dl;
    h0 = Hst[hb + (size_t)(s0 + 0) * kD];
    h1 = Hst[hb + (size_t)(s0 + 1) * kD];
    h2 = Hst[hb + (size_t)(s0 + 2) * kD];
    h3 = Hst[hb + (size_t)(s0 + 3) * kD];
  }
  float ds = D_skip[d0 + dl];
  size_t baseS = ((size_t)b * kLc + t0) * kS;
  size_t baseD = ((size_t)b * kLc + t0) * kD;

  for (int i = tid; i < clen * 16; i += 256) {
    int tt = i >> 4, dd = i & 15;
    xcl[tt][dd] = xc[baseD + (size_t)tt * kD + d0 + dd];
  }

  for (int sub = 0; sub < kQ; sub += 32) {
    int sl = min(32, clen - sub);
    if (sl <= 0) break;
    __syncthreads();
    {
      int nv = sl * (kS / 4);
      const float4* gA = (const float4*)(At + baseS + (size_t)sub * kS);
      const float4* gB = (const float4*)(Bt + baseS + (size_t)sub * kS);
      const float4* gC = (const float4*)(Ct + baseS + (size_t)sub * kS);
      for (int i = tid; i < nv; i += 256) {
        ((float4*)Al)[i] = gA[i];
        ((float4*)Bl)[i] = gB[i];
        ((float4*)Cl)[i] = gC[i];
      }
    }
    __syncthreads();
    for (int tt = 0; tt < sl; ++tt) {
      float xcv = xcl[sub + tt][dl];
      float4 a  = *(const float4*)&Al[tt][s0];
      float4 bv = *(const float4*)&Bl[tt][s0];
      float4 cv = *(const float4*)&Cl[tt][s0];
      h0 = fmaf(a.x, h0, bv.x * xcv);
      h1 = fmaf(a.y, h1, bv.y * xcv);
      h2 = fmaf(a.z, h2, bv.z * xcv);
      h3 = fmaf(a.w, h3, bv.w * xcv);
      float dot = fmaf(cv.x, h0, fmaf(cv.y, h1, fmaf(cv.z, h2, cv.w * h3)));
      dot = ror_add_<0x128>(dot);
      dot = ror_add_<0x124>(dot);
      dot = ror_add_<0x122>(dot);
      dot = ror_add_<0x121>(dot);
      if (sq == 0) yl[sub + tt][dl] = fmaf(ds, xcv, dot);
    }
  }
  __syncthreads();
  for (int i = tid; i < clen * 16; i += 256) {
    int tt = i >> 4, dd = i & 15;
    out[baseD + (size_t)tt * kD + d0 + dd] = yl[tt][dd];
  }
}

extern "C" void kernel_launch(void* const* d_in, const int* in_sizes, int n_in,
                              void* d_out, int out_size, void* d_ws, size_t ws_size,
                              hipStream_t stream) {
  const float* x      = (const float*)d_in[0];
  const float* a_hat  = (const float*)d_in[1];
  const float* W_U    = (const float*)d_in[2];
  const float* W_B    = (const float*)d_in[3];
  const float* b_B    = (const float*)d_in[4];
  const float* W_C    = (const float*)d_in[5];
  const float* b_C    = (const float*)d_in[6];
  const float* W_d1   = (const float*)d_in[7];
  const float* b_d1   = (const float*)d_in[8];
  const float* W_d2   = (const float*)d_in[9];
  const float* b_d2   = (const float*)d_in[10];
  const float* D_skip = (const float*)d_in[11];
  const float* conv_w = (const float*)d_in[12];
  const float* conv_b = (const float*)d_in[13];
  float* out = (float*)d_out;

  float* xc   = (float*)d_ws;                        // kM*kD
  float* raw  = xc + (size_t)kM * kD;                // kM*kNR
  float* At   = raw + (size_t)kM * kNR;              // kM*kS
  float* Bt   = At + (size_t)kM * kS;
  float* Ct   = Bt + (size_t)kM * kS;
  float* Bpre = Ct + (size_t)kM * kS;                // B*TC*Q*S
  float* dec  = Bpre + (size_t)kB * kTC * kQ * kS;   // B*TC*S
  float* Sc   = dec + (size_t)kB * kTC * kS;         // B*TC*S*D (becomes H)

  int convThreads = kB * kLc * (kD / 4);
  conv_kernel<<<(convThreads + 255) / 256, 256, 0, stream>>>(x, conv_w, conv_b, xc);

  dim3 ggrid((kM + 63) / 64, 4);
  gemm_kernel<<<ggrid, 256, 0, stream>>>(xc, W_U, W_B, W_C, W_d1, raw);

  epi_kernel<<<(kM * kS + 255) / 256, 256, 0, stream>>>(
      raw, b_B, b_C, b_d1, W_d2, b_d2, a_hat, At, Bt, Ct);

  prep_kernel<<<kB * kTC, 64, 0, stream>>>(At, Bt, Bpre, dec);

  dim3 pgrid(kD / 64, kB * kTC);
  pstate_kernel<<<pgrid, 256, 0, stream>>>(Bpre, xc, Sc);

  chscan_kernel<<<kB * kS, kD / 4, 0, stream>>>(dec, Sc);

  final_kernel<<<kB * kTC * 64, 256, 0, stream>>>(
      At, Bt, Ct, xc, Sc, D_skip, out);
}